// Round 5
// baseline (5577.434 us; speedup 1.0000x reference)
//
#include <hip/hip_runtime.h>
#include <hip/hip_bf16.h>

typedef unsigned int u32;
typedef unsigned short u16;

#define B_ 64
#define N_ 8192
#define DI 8
#define O_ 10
#define DO_ 16
#define OD 160          // O_*DO_
#define WROW_F 1280     // floats per W row (OD*DI)
#define CHUNK_N 16      // n staged per LDS chunk (16 waves -> 1 n per wave)
#define SROW 161        // padded fp32 row stride for s_lds (odd -> conflict-free)
#define VROW 162        // padded u16 row stride for v_lds (dword stride 81, odd)

static __device__ __forceinline__ float blo(u32 p) { return __uint_as_float(p << 16); }
static __device__ __forceinline__ float bhi(u32 p) { return __uint_as_float(p & 0xFFFF0000u); }

static __device__ __forceinline__ float dot8(const float* __restrict__ wp,
                                             const float* __restrict__ xf) {
    float u = 0.0f;
    #pragma unroll
    for (int i = 0; i < 8; ++i) u = fmaf(wp[i], xf[i], u);
    return u;
}

// PHASE 0: c = 0.1 uniform; accumulate 0.1*u_hat into s_lds.
// PHASE 1: t[o] = sum_d u_hat*v; softmax over o; accumulate c[o]*u_hat.
//          (rounds 1 & 2; v = v0 then v0+v1, since b2 = u.(v0+v1))
// TAIL 1: fp16 partial per block (no atomics).  TAIL 2: global atomicAdd.
// W is staged cooperatively into LDS (coalesced float4), compute reads it
// via wave-uniform broadcast ds_read_b128 -- W touched exactly once from HBM.
template <int PHASE, int NPER, int TAIL>
__global__ __launch_bounds__(1024, 4)
void caps_pass(const float* __restrict__ Xf, const float* __restrict__ Wf,
               const u16* __restrict__ Vb, float* __restrict__ Sout,
               _Float16* __restrict__ Sh) {
    __shared__ float w_buf[CHUNK_N * WROW_F];   // 81920 B
    __shared__ float s_lds[B_ * SROW];          // 41216 B
    __shared__ u16  v_lds[B_ * VROW];           // 20736 B  (total 143872 <= 160K)

    const int tid = threadIdx.x;
    for (int i = tid; i < B_ * SROW; i += 1024) s_lds[i] = 0.0f;
    if (PHASE > 0) {
        for (int i = tid; i < B_ * OD; i += 1024) {
            int b = i / OD, od = i - b * OD;
            v_lds[b * VROW + od] = Vb[i];
        }
    }

    const int b = tid & 63;                                   // lane = batch index
    const int w = __builtin_amdgcn_readfirstlane(tid >> 6);   // wave id 0..15

    #pragma unroll 1
    for (int c = 0; c < NPER / CHUNK_N; ++c) {
        const int n0 = blockIdx.x * NPER + c * CHUNK_N;
        __syncthreads();    // chunk c-1 consumed (and init visible, c==0)
        {
            const float4* src = (const float4*)(Wf + (size_t)n0 * WROW_F);
            float4* dst = (float4*)w_buf;
            #pragma unroll
            for (int j = 0; j < (CHUNK_N * WROW_F / 4) / 1024; ++j)   // 5 float4/thread
                dst[tid + j * 1024] = src[tid + j * 1024];
        }
        __syncthreads();

        const int n = n0 + w;                       // wave-uniform
        const float* wr = w_buf + w * WROW_F;       // wave-uniform LDS base

        const float4 x0 = *(const float4*)(Xf + ((size_t)b * N_ + n) * DI);
        const float4 x1 = *(const float4*)(Xf + ((size_t)b * N_ + n) * DI + 4);
        float xf[8] = {x0.x, x0.y, x0.z, x0.w, x1.x, x1.y, x1.z, x1.w};

        if (PHASE == 0) {
            #pragma unroll
            for (int o = 0; o < O_; ++o) {
                #pragma unroll
                for (int d = 0; d < DO_; ++d) {
                    const float u = dot8(wr + (o * DO_ + d) * DI, xf);
                    atomicAdd(&s_lds[b * SROW + o * DO_ + d], 0.1f * u);
                }
            }
        } else {
            // ---- logits t[o] = sum_d u_hat[o,d] * v[b,o,d]
            float t_[O_];
            #pragma unroll
            for (int o = 0; o < O_; ++o) {
                float acc = 0.0f;
                #pragma unroll
                for (int d2 = 0; d2 < 8; ++d2) {
                    const int d0 = 2 * d2;
                    const float* wp = wr + (o * DO_ + d0) * DI;
                    const float u0 = dot8(wp, xf);
                    const float u1 = dot8(wp + DI, xf);
                    const u32 vv = *(const u32*)&v_lds[b * VROW + o * DO_ + d0];
                    acc = fmaf(u0, blo(vv), acc);
                    acc = fmaf(u1, bhi(vv), acc);
                }
                t_[o] = acc;
            }
            // ---- softmax over the 10 out-capsules (|t| small, no max-sub)
            float e[O_], den = 0.0f;
            #pragma unroll
            for (int o = 0; o < O_; ++o) { e[o] = __expf(t_[o]); den += e[o]; }
            const float rinv = 1.0f / den;
            // ---- recompute u_hat, accumulate c[o]*u_hat
            #pragma unroll
            for (int o = 0; o < O_; ++o) {
                const float cc = e[o] * rinv;
                #pragma unroll
                for (int d = 0; d < DO_; ++d) {
                    const float u = dot8(wr + (o * DO_ + d) * DI, xf);
                    atomicAdd(&s_lds[b * SROW + o * DO_ + d], cc * u);
                }
            }
        }
    }
    __syncthreads();
    if (TAIL == 2) {
        for (int i = tid; i < B_ * OD; i += 1024) {
            int bb = i / OD, od = i - bb * OD;
            atomicAdd(&Sout[i], s_lds[bb * SROW + od]);
        }
    } else {
        _Float16* my = Sh + (size_t)blockIdx.x * (B_ * OD);
        for (int i = tid; i < B_ * OD; i += 1024) {
            int bb = i / OD, od = i - bb * OD;
            my[i] = (_Float16)s_lds[bb * SROW + od];
        }
    }
}

// Fused cross-block reduce + squash (squash norm over OUT-CAPSULE axis, per (b,d)).
// PHASE 0: V0f=v0 fp32, Vb=bf16(v0). PHASE 1: Vb=bf16(v0+v1). PHASE 2: out=v2 fp32.
template <int PHASE>
__global__ __launch_bounds__(192)
void caps_reduce_fin(const _Float16* __restrict__ Sp, int nparts,
                     float* __restrict__ V0f, u16* __restrict__ Vb,
                     float* __restrict__ out) {
    __shared__ float s_s[OD];
    __shared__ float s_scale[DO_];
    const int b = blockIdx.x;
    const int t = threadIdx.x;
    if (t < OD) {
        float acc = 0.0f;
        const _Float16* p0 = Sp + b * OD + t;
        #pragma unroll 8
        for (int p = 0; p < nparts; ++p) acc += (float)p0[(size_t)p * (B_ * OD)];
        s_s[t] = acc;
    }
    __syncthreads();
    if (t < DO_) {
        float norm = 0.0f;
        #pragma unroll
        for (int o = 0; o < O_; ++o) { float x = s_s[o * DO_ + t]; norm = fmaf(x, x, norm); }
        s_scale[t] = norm / (1.0f + norm) * rsqrtf(norm + 1e-9f);
    }
    __syncthreads();
    if (t < OD) {
        const float v = s_s[t] * s_scale[t & 15];
        const int idx = b * OD + t;
        if (PHASE == 0) {
            V0f[idx] = v;
            __hip_bfloat16 h = __float2bfloat16(v);
            Vb[idx] = *(const u16*)&h;
        } else if (PHASE == 1) {
            const float vs = V0f[idx] + v;
            __hip_bfloat16 h = __float2bfloat16(vs);
            Vb[idx] = *(const u16*)&h;
        } else {
            out[idx] = v;
        }
    }
}

// Finalize for the atomic fallback (also zeroes S for the next pass).
template <int PHASE>
__global__ __launch_bounds__(1024)
void caps_finalize(float* __restrict__ S, float* __restrict__ V0f,
                   u16* __restrict__ Vb, float* __restrict__ out) {
    const int tid = threadIdx.x;      // 1024 = 64 b * 16 d
    const int b = tid >> 4, d = tid & 15;
    float sv[O_];
    float norm = 0.0f;
    #pragma unroll
    for (int o = 0; o < O_; ++o) {
        sv[o] = S[b * OD + o * DO_ + d];
        norm = fmaf(sv[o], sv[o], norm);
    }
    const float scale = norm / (1.0f + norm) * rsqrtf(norm + 1e-9f);
    #pragma unroll
    for (int o = 0; o < O_; ++o) {
        const int idx = b * OD + o * DO_ + d;
        const float v = scale * sv[o];
        if (PHASE == 0) {
            V0f[idx] = v;
            __hip_bfloat16 h = __float2bfloat16(v);
            Vb[idx] = *(const u16*)&h;
            S[idx] = 0.0f;
        } else if (PHASE == 1) {
            const float vs = V0f[idx] + v;
            __hip_bfloat16 h = __float2bfloat16(vs);
            Vb[idx] = *(const u16*)&h;
            S[idx] = 0.0f;
        } else {
            out[idx] = v;
        }
    }
}

extern "C" void kernel_launch(void* const* d_in, const int* in_sizes, int n_in,
                              void* d_out, int out_size, void* d_ws, size_t ws_size,
                              hipStream_t stream) {
    const float* Xf = (const float*)d_in[0];   // x: [64, 8192, 8] fp32
    const float* Wf = (const float*)d_in[1];   // W: [1, 8192, 10, 16, 8] fp32
    float* out = (float*)d_out;

    const size_t vbytes = (size_t)B_ * OD;                 // 10240 elems
    const size_t base = vbytes * 4 + vbytes * 2;           // V0f fp32 + Vb bf16 = 61440 B
    const size_t needB = base + (size_t)256 * vbytes * 2;  // 5,304,320 B (fp16 partials x256)
    const size_t needC = base + (size_t)128 * vbytes * 2;  // 2,682,880 B (fp16 partials x128)

    float* V0f = (float*)d_ws;
    u16* Vb = (u16*)(V0f + vbytes);
    const dim3 rgrid(B_), rblk(192), blk(1024);

    if (ws_size >= needB) {
        // tier B: 256 blocks, fp16 partials, no atomics
        _Float16* P = (_Float16*)((char*)d_ws + base);
        const dim3 grid(256);
        caps_pass<0, 32, 1><<<grid, blk, 0, stream>>>(Xf, Wf, nullptr, nullptr, P);
        caps_reduce_fin<0><<<rgrid, rblk, 0, stream>>>(P, 256, V0f, Vb, nullptr);
        caps_pass<1, 32, 1><<<grid, blk, 0, stream>>>(Xf, Wf, Vb, nullptr, P);
        caps_reduce_fin<1><<<rgrid, rblk, 0, stream>>>(P, 256, V0f, Vb, nullptr);
        caps_pass<1, 32, 1><<<grid, blk, 0, stream>>>(Xf, Wf, Vb, nullptr, P);
        caps_reduce_fin<2><<<rgrid, rblk, 0, stream>>>(P, 256, nullptr, nullptr, out);
    } else if (ws_size >= needC) {
        // tier C: 128 blocks (64 n each), fp16 partials, no atomics
        _Float16* P = (_Float16*)((char*)d_ws + base);
        const dim3 grid(128);
        caps_pass<0, 64, 1><<<grid, blk, 0, stream>>>(Xf, Wf, nullptr, nullptr, P);
        caps_reduce_fin<0><<<rgrid, rblk, 0, stream>>>(P, 128, V0f, Vb, nullptr);
        caps_pass<1, 64, 1><<<grid, blk, 0, stream>>>(Xf, Wf, Vb, nullptr, P);
        caps_reduce_fin<1><<<rgrid, rblk, 0, stream>>>(P, 128, V0f, Vb, nullptr);
        caps_pass<1, 64, 1><<<grid, blk, 0, stream>>>(Xf, Wf, Vb, nullptr, P);
        caps_reduce_fin<2><<<rgrid, rblk, 0, stream>>>(P, 128, nullptr, nullptr, out);
    } else {
        // tier D: global atomic accumulator (proven-correct), new fast compute loop
        float* S = (float*)((char*)d_ws + base);           // 40960 B (total 102400, known to fit)
        const dim3 grid(256), one(1);
        hipMemsetAsync(S, 0, vbytes * sizeof(float), stream);
        caps_pass<0, 32, 2><<<grid, blk, 0, stream>>>(Xf, Wf, nullptr, S, nullptr);
        caps_finalize<0><<<one, blk, 0, stream>>>(S, V0f, Vb, nullptr);
        caps_pass<1, 32, 2><<<grid, blk, 0, stream>>>(Xf, Wf, Vb, S, nullptr);
        caps_finalize<1><<<one, blk, 0, stream>>>(S, V0f, Vb, nullptr);
        caps_pass<1, 32, 2><<<grid, blk, 0, stream>>>(Xf, Wf, Vb, S, nullptr);
        caps_finalize<2><<<one, blk, 0, stream>>>(S, nullptr, nullptr, out);
    }
}

// Round 6
// 1573.792 us; speedup vs baseline: 3.5439x; 3.5439x over previous
//
#include <hip/hip_runtime.h>
#include <hip/hip_bf16.h>

typedef unsigned int u32;
typedef unsigned short u16;

#define B_ 64
#define N_ 8192
#define DI 8
#define O_ 10
#define DO_ 16
#define OD 160          // O_*DO_
#define NCHUNK 32       // n per block; grid = N_/NCHUNK = 256 blocks
#define NPART 256       // number of partial buffers (= grid size)
#define SROW 161        // padded fp32 row stride for s_lds (odd -> 2 lanes/bank, free)
#define VROW 162        // padded u16 row stride for v_lds (dword stride 81, odd)

static __device__ __forceinline__ float blo(u32 p) { return __uint_as_float(p << 16); }
static __device__ __forceinline__ float bhi(u32 p) { return __uint_as_float(p & 0xFFFF0000u); }

// R4's proven-fast compute loop (520 us, no scratch, 52 VGPR): lane = b,
// wave-uniform n, W via scalar loads (SGPR-operand FMAs).
// PHASE 0: c = 0.1 uniform; accumulate 0.1*u_hat into s_lds.
// PHASE 1: t[o] = sum_d u_hat*v; softmax over o; accumulate c[o]*u_hat.
//          (rounds 1 & 2; v = v0 then v0+v1, since b2 = u.(v0+v1))
// TAIL 1: fp16 partial per block, plain coalesced stores (proven R5).
// TAIL 2: global atomicAdd fallback (proven R3).
template <int PHASE, int TAIL>
__global__ __launch_bounds__(1024, 4)
void caps_pass(const float* __restrict__ Xf, const float* __restrict__ Wf,
               const u16* __restrict__ Vb, float* __restrict__ Sout,
               _Float16* __restrict__ Sh) {
    __shared__ float s_lds[B_ * SROW];          // 41216 B
    __shared__ u16  v_lds[B_ * VROW];           // 20736 B (total 61952)

    const int tid = threadIdx.x;
    for (int i = tid; i < B_ * SROW; i += 1024) s_lds[i] = 0.0f;
    if (PHASE > 0) {
        for (int i = tid; i < B_ * OD; i += 1024) {
            int b = i / OD, od = i - b * OD;
            v_lds[b * VROW + od] = Vb[i];
        }
    }
    __syncthreads();

    const int b = tid & 63;                                   // lane = batch index
    const int w = __builtin_amdgcn_readfirstlane(tid >> 6);   // wave id 0..15

    #pragma unroll 1
    for (int k = 0; k < NCHUNK / 16; ++k) {
        const int n = blockIdx.x * NCHUNK + w + 16 * k;       // wave-uniform n

        const float4 x0 = *(const float4*)(Xf + ((size_t)b * N_ + n) * DI);
        const float4 x1 = *(const float4*)(Xf + ((size_t)b * N_ + n) * DI + 4);
        float xf[8];
        xf[0] = x0.x; xf[1] = x0.y; xf[2] = x0.z; xf[3] = x0.w;
        xf[4] = x1.x; xf[5] = x1.y; xf[6] = x1.z; xf[7] = x1.w;

        // W[n][o][d][i] row base: wave-uniform -> scalar loads
        const float* wrow = Wf + (size_t)n * (O_ * DO_ * DI);

        if (PHASE == 0) {
            #pragma unroll
            for (int o = 0; o < O_; ++o) {
                #pragma unroll
                for (int d = 0; d < DO_; ++d) {
                    const float* wp = wrow + (o * DO_ + d) * DI;
                    float u = 0.0f;
                    #pragma unroll
                    for (int ii = 0; ii < DI; ++ii) u = fmaf(wp[ii], xf[ii], u);
                    atomicAdd(&s_lds[b * SROW + o * DO_ + d], 0.1f * u);
                }
            }
        } else {
            // ---- logits t[o] = sum_d u_hat[o,d] * v[b,o,d]
            float t_[O_];
            #pragma unroll
            for (int o = 0; o < O_; ++o) {
                float acc = 0.0f;
                #pragma unroll
                for (int d2 = 0; d2 < 8; ++d2) {
                    const int d0 = 2 * d2;
                    const float* wp = wrow + (o * DO_ + d0) * DI;
                    float u0 = 0.0f, u1 = 0.0f;
                    #pragma unroll
                    for (int ii = 0; ii < DI; ++ii) {
                        u0 = fmaf(wp[ii], xf[ii], u0);
                        u1 = fmaf(wp[DI + ii], xf[ii], u1);
                    }
                    const u32 vv = *(const u32*)&v_lds[b * VROW + o * DO_ + d0];
                    acc = fmaf(u0, blo(vv), acc);
                    acc = fmaf(u1, bhi(vv), acc);
                }
                t_[o] = acc;
            }
            // ---- softmax over the 10 out-capsules (|t| small, no max-sub)
            float e[O_], den = 0.0f;
            #pragma unroll
            for (int o = 0; o < O_; ++o) { e[o] = __expf(t_[o]); den += e[o]; }
            const float rinv = 1.0f / den;
            // ---- recompute u_hat, accumulate c[o]*u_hat
            #pragma unroll
            for (int o = 0; o < O_; ++o) {
                const float cc = e[o] * rinv;
                #pragma unroll
                for (int d = 0; d < DO_; ++d) {
                    const float* wp = wrow + (o * DO_ + d) * DI;
                    float u = 0.0f;
                    #pragma unroll
                    for (int ii = 0; ii < DI; ++ii) u = fmaf(wp[ii], xf[ii], u);
                    atomicAdd(&s_lds[b * SROW + o * DO_ + d], cc * u);
                }
            }
        }
    }
    __syncthreads();
    if (TAIL == 2) {
        for (int i = tid; i < B_ * OD; i += 1024) {
            int bb = i / OD, od = i - bb * OD;
            atomicAdd(&Sout[i], s_lds[bb * SROW + od]);
        }
    } else {
        // fp16 partial stream: plain coalesced stores, no atomics
        _Float16* my = Sh + (size_t)blockIdx.x * (B_ * OD);
        for (int i = tid; i < B_ * OD; i += 1024) {
            int bb = i / OD, od = i - bb * OD;
            my[i] = (_Float16)s_lds[bb * SROW + od];
        }
    }
}

// Fused cross-block reduce + squash (norm over OUT-CAPSULE axis, per (b,d)).
// PHASE 0: V0f=v0 fp32, Vb=bf16(v0). PHASE 1: Vb=bf16(v0+v1). PHASE 2: out=v2 fp32.
// (Proven correct in R5.)
template <int PHASE>
__global__ __launch_bounds__(192)
void caps_reduce_fin(const _Float16* __restrict__ Sp, int nparts,
                     float* __restrict__ V0f, u16* __restrict__ Vb,
                     float* __restrict__ out) {
    __shared__ float s_s[OD];
    __shared__ float s_scale[DO_];
    const int b = blockIdx.x;
    const int t = threadIdx.x;
    if (t < OD) {
        float acc = 0.0f;
        const _Float16* p0 = Sp + b * OD + t;
        #pragma unroll 8
        for (int p = 0; p < nparts; ++p) acc += (float)p0[(size_t)p * (B_ * OD)];
        s_s[t] = acc;
    }
    __syncthreads();
    if (t < DO_) {
        float norm = 0.0f;
        #pragma unroll
        for (int o = 0; o < O_; ++o) { float x = s_s[o * DO_ + t]; norm = fmaf(x, x, norm); }
        s_scale[t] = norm / (1.0f + norm) * rsqrtf(norm + 1e-9f);
    }
    __syncthreads();
    if (t < OD) {
        const float v = s_s[t] * s_scale[t & 15];
        const int idx = b * OD + t;
        if (PHASE == 0) {
            V0f[idx] = v;
            __hip_bfloat16 h = __float2bfloat16(v);
            Vb[idx] = *(const u16*)&h;
        } else if (PHASE == 1) {
            const float vs = V0f[idx] + v;
            __hip_bfloat16 h = __float2bfloat16(vs);
            Vb[idx] = *(const u16*)&h;
        } else {
            out[idx] = v;
        }
    }
}

// Finalize for the atomic fallback (also zeroes S for the next pass).
template <int PHASE>
__global__ __launch_bounds__(1024)
void caps_finalize(float* __restrict__ S, float* __restrict__ V0f,
                   u16* __restrict__ Vb, float* __restrict__ out) {
    const int tid = threadIdx.x;      // 1024 = 64 b * 16 d
    const int b = tid >> 4, d = tid & 15;
    float sv[O_];
    float norm = 0.0f;
    #pragma unroll
    for (int o = 0; o < O_; ++o) {
        sv[o] = S[b * OD + o * DO_ + d];
        norm = fmaf(sv[o], sv[o], norm);
    }
    const float scale = norm / (1.0f + norm) * rsqrtf(norm + 1e-9f);
    #pragma unroll
    for (int o = 0; o < O_; ++o) {
        const int idx = b * OD + o * DO_ + d;
        const float v = scale * sv[o];
        if (PHASE == 0) {
            V0f[idx] = v;
            __hip_bfloat16 h = __float2bfloat16(v);
            Vb[idx] = *(const u16*)&h;
            S[idx] = 0.0f;
        } else if (PHASE == 1) {
            const float vs = V0f[idx] + v;
            __hip_bfloat16 h = __float2bfloat16(vs);
            Vb[idx] = *(const u16*)&h;
            S[idx] = 0.0f;
        } else {
            out[idx] = v;
        }
    }
}

extern "C" void kernel_launch(void* const* d_in, const int* in_sizes, int n_in,
                              void* d_out, int out_size, void* d_ws, size_t ws_size,
                              hipStream_t stream) {
    const float* Xf = (const float*)d_in[0];   // x: [64, 8192, 8] fp32
    const float* Wf = (const float*)d_in[1];   // W: [1, 8192, 10, 16, 8] fp32
    float* out = (float*)d_out;

    const size_t velems = (size_t)B_ * OD;                   // 10240
    const size_t base = velems * 4 + velems * 2;             // V0f fp32 + Vb bf16
    const size_t need = base + (size_t)NPART * velems * 2;   // + fp16 partials = 5,304,320 B

    float* V0f = (float*)d_ws;
    u16* Vb = (u16*)(V0f + velems);
    const dim3 grid(N_ / NCHUNK), blk(1024), rgrid(B_), rblk(192);

    if (ws_size >= need) {
        // fast path: fp16 per-block partials (proven available in R5: ws >= 5.3 MB)
        _Float16* P = (_Float16*)((char*)d_ws + base);
        caps_pass<0, 1><<<grid, blk, 0, stream>>>(Xf, Wf, nullptr, nullptr, P);
        caps_reduce_fin<0><<<rgrid, rblk, 0, stream>>>(P, NPART, V0f, Vb, nullptr);
        caps_pass<1, 1><<<grid, blk, 0, stream>>>(Xf, Wf, Vb, nullptr, P);
        caps_reduce_fin<1><<<rgrid, rblk, 0, stream>>>(P, NPART, V0f, Vb, nullptr);
        caps_pass<1, 1><<<grid, blk, 0, stream>>>(Xf, Wf, Vb, nullptr, P);
        caps_reduce_fin<2><<<rgrid, rblk, 0, stream>>>(P, NPART, nullptr, nullptr, out);
    } else {
        // fallback: global atomic accumulator (proven R3 path)
        float* S = (float*)((char*)d_ws + base);
        const dim3 one(1);
        hipMemsetAsync(S, 0, velems * sizeof(float), stream);
        caps_pass<0, 2><<<grid, blk, 0, stream>>>(Xf, Wf, nullptr, S, nullptr);
        caps_finalize<0><<<one, blk, 0, stream>>>(S, V0f, Vb, nullptr);
        caps_pass<1, 2><<<grid, blk, 0, stream>>>(Xf, Wf, Vb, S, nullptr);
        caps_finalize<1><<<one, blk, 0, stream>>>(S, V0f, Vb, nullptr);
        caps_pass<1, 2><<<grid, blk, 0, stream>>>(Xf, Wf, Vb, S, nullptr);
        caps_finalize<2><<<one, blk, 0, stream>>>(S, nullptr, nullptr, out);
    }
}

// Round 7
// 1461.882 us; speedup vs baseline: 3.8152x; 1.0766x over previous
//
#include <hip/hip_runtime.h>
#include <hip/hip_bf16.h>

typedef unsigned int u32;
typedef unsigned short u16;

#define B_ 64
#define N_ 8192
#define DI 8
#define O_ 10
#define DO_ 16
#define OD 160          // O_*DO_
#define NCHUNK 32       // n per block; grid = 256 blocks
#define NPART 256       // partial buffers (= grid)  -- ws >= 5.3 MB proven in R5/R6
#define SROW 168        // s_lds row pad: bank=(8*b4+c)%32 exact 2-way -> free
#define VROW 162        // v_lds u16 row pad

static __device__ __forceinline__ float blo(u32 p) { return __uint_as_float(p << 16); }

template <int CTRL>
static __device__ __forceinline__ float dpp_add(float x) {
    int y = __builtin_amdgcn_update_dpp(0, __float_as_int(x), CTRL, 0xF, 0xF, true);
    return x + __int_as_float(y);
}
// Sum across the 16 lanes of each DPP row (row = lanes 16k..16k+15 = one b4
// group); result replicated to all 16 lanes. VALU-pipe only (no LDS).
static __device__ __forceinline__ float row16_sum(float x) {
    x = dpp_add<0xB1>(x);    // quad_perm(1,0,3,2): + lane^1
    x = dpp_add<0x4E>(x);    // quad_perm(2,3,0,1): + lane^2
    x = dpp_add<0x124>(x);   // row_ror:4  -> quad sums
    x = dpp_add<0x128>(x);   // row_ror:8  -> full row sum
    return x;
}

static __device__ __forceinline__ float dot8(const float4& a, const float4& b,
                                             const float4& x0, const float4& x1) {
    float s = 0.0f;
    s = fmaf(a.x, x0.x, s); s = fmaf(a.y, x0.y, s);
    s = fmaf(a.z, x0.z, s); s = fmaf(a.w, x0.w, s);
    s = fmaf(b.x, x1.x, s); s = fmaf(b.y, x1.y, s);
    s = fmaf(b.z, x1.z, s); s = fmaf(b.w, x1.w, s);
    return s;
}

// Lane mapping: lane = (b4 = lane>>4, c = lane&15).  Wave owns one n at a
// time; W row held in 80 VGPRs (lane c holds rows od = 16*oo + c, dedup'd
// coalesced float4 loads).  b-loop t=0..15: b = b4 + 4t.
// PHASE 0: c_route = 0.1 uniform.  PHASE 1: logits via DPP row-reduce,
// softmax over o in-register, weighting reuses live u[] regs.
// TAIL 1: fp16 partial per block (proven R5/R6).  TAIL 2: global atomics.
template <int PHASE, int TAIL>
__global__ __launch_bounds__(512, 2)
void caps_pass(const float* __restrict__ Xf, const float* __restrict__ Wf,
               const u16* __restrict__ Vb, float* __restrict__ Sout,
               _Float16* __restrict__ Sh) {
    __shared__ float s_lds[B_ * SROW];          // 43008 B
    __shared__ u16  v_lds[B_ * VROW];           // 20736 B (total 63744)

    const int tid = threadIdx.x;
    for (int i = tid; i < B_ * SROW; i += 512) s_lds[i] = 0.0f;
    if (PHASE > 0) {
        for (int i = tid; i < B_ * OD; i += 512) {
            int b = i / OD, od = i - b * OD;
            v_lds[b * VROW + od] = Vb[i];
        }
    }
    __syncthreads();

    const int lane = tid & 63;
    const int b4 = lane >> 4;                                 // 0..3
    const int c  = lane & 15;                                 // 0..15 (= d)
    const int w  = __builtin_amdgcn_readfirstlane(tid >> 6);  // wave 0..7

    #pragma unroll 1
    for (int k = 0; k < NCHUNK / 8; ++k) {
        const int n = blockIdx.x * NCHUNK + w + 8 * k;        // wave-uniform
        const float* wrow = Wf + (size_t)n * (OD * DI);

        // W row -> regs: lane c covers od = 16*oo + c, all 8 i.
        // 16 lanes x 32 B = 512 B contiguous per load pair; 20-deep MLP.
        float4 wA[O_], wB[O_];
        #pragma unroll
        for (int oo = 0; oo < O_; ++oo) {
            const float* p = wrow + (oo * DO_ + c) * DI;
            wA[oo] = *(const float4*)p;
            wB[oo] = *(const float4*)(p + 4);
        }

        #pragma unroll 1
        for (int t = 0; t < 16; ++t) {
            const int b = b4 + 4 * t;
            const float* xp = Xf + ((size_t)b * N_ + n) * DI;
            const float4 x0 = *(const float4*)xp;
            const float4 x1 = *(const float4*)(xp + 4);

            float u[O_];                       // u_hat[b, o=oo, d=c]
            #pragma unroll
            for (int oo = 0; oo < O_; ++oo) u[oo] = dot8(wA[oo], wB[oo], x0, x1);

            if (PHASE == 0) {
                #pragma unroll
                for (int oo = 0; oo < O_; ++oo)
                    atomicAdd(&s_lds[b * SROW + oo * DO_ + c], 0.1f * u[oo]);
            } else {
                // logits: t[o] = sum_d u_hat * v  (DPP reduce over the 16 d-lanes)
                float tl[O_];
                #pragma unroll
                for (int oo = 0; oo < O_; ++oo) {
                    const float vv = blo((u32)v_lds[b * VROW + oo * DO_ + c]);
                    tl[oo] = row16_sum(u[oo] * vv);
                }
                // softmax over the 10 out-capsules (|t| small, no max-sub)
                float den = 0.0f;
                #pragma unroll
                for (int oo = 0; oo < O_; ++oo) { tl[oo] = __expf(tl[oo]); den += tl[oo]; }
                const float rinv = 1.0f / den;
                // weighting: reuse live u[] regs (no recompute)
                #pragma unroll
                for (int oo = 0; oo < O_; ++oo)
                    atomicAdd(&s_lds[b * SROW + oo * DO_ + c], (tl[oo] * rinv) * u[oo]);
            }
        }
    }
    __syncthreads();
    if (TAIL == 2) {
        for (int i = tid; i < B_ * OD; i += 512) {
            int bb = i / OD, od = i - bb * OD;
            atomicAdd(&Sout[i], s_lds[bb * SROW + od]);
        }
    } else {
        _Float16* my = Sh + (size_t)blockIdx.x * (B_ * OD);
        for (int i = tid; i < B_ * OD; i += 512) {
            int bb = i / OD, od = i - bb * OD;
            my[i] = (_Float16)s_lds[bb * SROW + od];
        }
    }
}

// Fused cross-block reduce + squash (norm over OUT-CAPSULE axis, per (b,d)).
// PHASE 0: V0f=v0 fp32, Vb=bf16(v0). PHASE 1: Vb=bf16(v0+v1). PHASE 2: out fp32.
// (Proven correct R5/R6.)
template <int PHASE>
__global__ __launch_bounds__(192)
void caps_reduce_fin(const _Float16* __restrict__ Sp, int nparts,
                     float* __restrict__ V0f, u16* __restrict__ Vb,
                     float* __restrict__ out) {
    __shared__ float s_s[OD];
    __shared__ float s_scale[DO_];
    const int b = blockIdx.x;
    const int t = threadIdx.x;
    if (t < OD) {
        float acc = 0.0f;
        const _Float16* p0 = Sp + b * OD + t;
        #pragma unroll 8
        for (int p = 0; p < nparts; ++p) acc += (float)p0[(size_t)p * (B_ * OD)];
        s_s[t] = acc;
    }
    __syncthreads();
    if (t < DO_) {
        float norm = 0.0f;
        #pragma unroll
        for (int o = 0; o < O_; ++o) { float x = s_s[o * DO_ + t]; norm = fmaf(x, x, norm); }
        s_scale[t] = norm / (1.0f + norm) * rsqrtf(norm + 1e-9f);
    }
    __syncthreads();
    if (t < OD) {
        const float v = s_s[t] * s_scale[t & 15];
        const int idx = b * OD + t;
        if (PHASE == 0) {
            V0f[idx] = v;
            __hip_bfloat16 h = __float2bfloat16(v);
            Vb[idx] = *(const u16*)&h;
        } else if (PHASE == 1) {
            const float vs = V0f[idx] + v;
            __hip_bfloat16 h = __float2bfloat16(vs);
            Vb[idx] = *(const u16*)&h;
        } else {
            out[idx] = v;
        }
    }
}

// Finalize for the atomic fallback (also zeroes S for the next pass).
template <int PHASE>
__global__ __launch_bounds__(1024)
void caps_finalize(float* __restrict__ S, float* __restrict__ V0f,
                   u16* __restrict__ Vb, float* __restrict__ out) {
    const int tid = threadIdx.x;      // 1024 = 64 b * 16 d
    const int b = tid >> 4, d = tid & 15;
    float sv[O_];
    float norm = 0.0f;
    #pragma unroll
    for (int o = 0; o < O_; ++o) {
        sv[o] = S[b * OD + o * DO_ + d];
        norm = fmaf(sv[o], sv[o], norm);
    }
    const float scale = norm / (1.0f + norm) * rsqrtf(norm + 1e-9f);
    #pragma unroll
    for (int o = 0; o < O_; ++o) {
        const int idx = b * OD + o * DO_ + d;
        const float v = scale * sv[o];
        if (PHASE == 0) {
            V0f[idx] = v;
            __hip_bfloat16 h = __float2bfloat16(v);
            Vb[idx] = *(const u16*)&h;
            S[idx] = 0.0f;
        } else if (PHASE == 1) {
            const float vs = V0f[idx] + v;
            __hip_bfloat16 h = __float2bfloat16(vs);
            Vb[idx] = *(const u16*)&h;
            S[idx] = 0.0f;
        } else {
            out[idx] = v;
        }
    }
}

extern "C" void kernel_launch(void* const* d_in, const int* in_sizes, int n_in,
                              void* d_out, int out_size, void* d_ws, size_t ws_size,
                              hipStream_t stream) {
    const float* Xf = (const float*)d_in[0];   // x: [64, 8192, 8] fp32
    const float* Wf = (const float*)d_in[1];   // W: [1, 8192, 10, 16, 8] fp32
    float* out = (float*)d_out;

    const size_t velems = (size_t)B_ * OD;                   // 10240
    const size_t base = velems * 4 + velems * 2;             // V0f fp32 + Vb bf16
    const size_t need = base + (size_t)NPART * velems * 2;   // 5,304,320 B (proven fits)

    float* V0f = (float*)d_ws;
    u16* Vb = (u16*)(V0f + velems);
    const dim3 grid(N_ / NCHUNK), blk(512), rgrid(B_), rblk(192);

    if (ws_size >= need) {
        // fast path: fp16 per-block partials (proven)
        _Float16* P = (_Float16*)((char*)d_ws + base);
        caps_pass<0, 1><<<grid, blk, 0, stream>>>(Xf, Wf, nullptr, nullptr, P);
        caps_reduce_fin<0><<<rgrid, rblk, 0, stream>>>(P, NPART, V0f, Vb, nullptr);
        caps_pass<1, 1><<<grid, blk, 0, stream>>>(Xf, Wf, Vb, nullptr, P);
        caps_reduce_fin<1><<<rgrid, rblk, 0, stream>>>(P, NPART, V0f, Vb, nullptr);
        caps_pass<1, 1><<<grid, blk, 0, stream>>>(Xf, Wf, Vb, nullptr, P);
        caps_reduce_fin<2><<<rgrid, rblk, 0, stream>>>(P, NPART, nullptr, nullptr, out);
    } else {
        // fallback: global atomic accumulator (proven R3 structure)
        float* S = (float*)((char*)d_ws + base);
        const dim3 one(1), fblk(1024);
        hipMemsetAsync(S, 0, velems * sizeof(float), stream);
        caps_pass<0, 2><<<grid, blk, 0, stream>>>(Xf, Wf, nullptr, S, nullptr);
        caps_finalize<0><<<one, fblk, 0, stream>>>(S, V0f, Vb, nullptr);
        caps_pass<1, 2><<<grid, blk, 0, stream>>>(Xf, Wf, Vb, S, nullptr);
        caps_finalize<1><<<one, fblk, 0, stream>>>(S, V0f, Vb, nullptr);
        caps_pass<1, 2><<<grid, blk, 0, stream>>>(Xf, Wf, Vb, S, nullptr);
        caps_finalize<2><<<one, fblk, 0, stream>>>(S, nullptr, nullptr, out);
    }
}

// Round 8
// 1438.181 us; speedup vs baseline: 3.8781x; 1.0165x over previous
//
#include <hip/hip_runtime.h>
#include <hip/hip_bf16.h>

typedef unsigned int u32;
typedef unsigned short u16;

#define B_ 64
#define N_ 8192
#define DI 8
#define O_ 10
#define DO_ 16
#define OD 160          // O_*DO_
#define NCHUNK 32       // n per block; grid = 256 blocks
#define NPART 256       // partial buffers (= grid)  -- ws >= 5.3 MB proven in R5/R6
#define SROW 168        // s_lds row pad: bank=(8*b4+c)%32 exact 2-way -> free
#define VROW 162        // v_lds u16 row pad

static __device__ __forceinline__ float blo(u32 p) { return __uint_as_float(p << 16); }

template <int CTRL>
static __device__ __forceinline__ float dpp_add(float x) {
    int y = __builtin_amdgcn_update_dpp(0, __float_as_int(x), CTRL, 0xF, 0xF, true);
    return x + __int_as_float(y);
}
// Sum across the 16 lanes of each DPP row; result replicated to all 16 lanes.
static __device__ __forceinline__ float row16_sum(float x) {
    x = dpp_add<0xB1>(x);    // quad_perm(1,0,3,2): + lane^1
    x = dpp_add<0x4E>(x);    // quad_perm(2,3,0,1): + lane^2
    x = dpp_add<0x124>(x);   // row_ror:4  -> quad sums
    x = dpp_add<0x128>(x);   // row_ror:8  -> full row sum
    return x;
}

static __device__ __forceinline__ float dot8(const float4& a, const float4& b,
                                             const float4& x0, const float4& x1) {
    float s = 0.0f;
    s = fmaf(a.x, x0.x, s); s = fmaf(a.y, x0.y, s);
    s = fmaf(a.z, x0.z, s); s = fmaf(a.w, x0.w, s);
    s = fmaf(b.x, x1.x, s); s = fmaf(b.y, x1.y, s);
    s = fmaf(b.z, x1.z, s); s = fmaf(b.w, x1.w, s);
    return s;
}

// Opaque register barrier: forces v to live in VGPRs here and prevents the
// compiler from sinking/rematerializing the producing loads into later loops.
static __device__ __forceinline__ void pin4(float4& v) {
    asm volatile("" : "+v"(v.x), "+v"(v.y), "+v"(v.z), "+v"(v.w));
}

// Lane mapping: lane = (b4 = lane>>4, c = lane&15).  Wave owns one n at a
// time; W row PINNED in 80 VGPRs (lane c holds rows od = 16*oo + c).
// b-loop t=0..15: b = b4 + 4t, with x prefetched one iteration ahead.
// PHASE 0: c_route = 0.1 uniform.  PHASE 1: logits via DPP row-reduce,
// softmax over o in-register, weighting reuses live u[] regs.
// TAIL 1: fp16 partial per block (proven R5-R7).  TAIL 2: global atomics.
template <int PHASE, int TAIL>
__global__ __launch_bounds__(512, 2)
void caps_pass(const float* __restrict__ Xf, const float* __restrict__ Wf,
               const u16* __restrict__ Vb, float* __restrict__ Sout,
               _Float16* __restrict__ Sh) {
    __shared__ float s_lds[B_ * SROW];          // 43008 B
    __shared__ u16  v_lds[B_ * VROW];           // 20736 B (total 63744)

    const int tid = threadIdx.x;
    for (int i = tid; i < B_ * SROW; i += 512) s_lds[i] = 0.0f;
    if (PHASE > 0) {
        for (int i = tid; i < B_ * OD; i += 512) {
            int b = i / OD, od = i - b * OD;
            v_lds[b * VROW + od] = Vb[i];
        }
    }
    __syncthreads();

    const int lane = tid & 63;
    const int b4 = lane >> 4;                                 // 0..3
    const int c  = lane & 15;                                 // 0..15 (= d)
    const int w  = __builtin_amdgcn_readfirstlane(tid >> 6);  // wave 0..7

    #pragma unroll 1
    for (int k = 0; k < NCHUNK / 8; ++k) {
        const int n = blockIdx.x * NCHUNK + w + 8 * k;        // wave-uniform
        const float* wrow = Wf + (size_t)n * (OD * DI);

        // ---- W row -> 80 pinned VGPRs. 20 independent dwordx4 loads issue
        // back-to-back (20-deep MLP): ONE latency window per n, not per t.
        float4 wA[O_], wB[O_];
        #pragma unroll
        for (int oo = 0; oo < O_; ++oo) {
            const float* p = wrow + (oo * DO_ + c) * DI;
            wA[oo] = *(const float4*)p;
            wB[oo] = *(const float4*)(p + 4);
        }
        #pragma unroll
        for (int oo = 0; oo < O_; ++oo) { pin4(wA[oo]); pin4(wB[oo]); }

        // ---- x prefetch pipeline: load t=0 before the loop
        const float* xp0 = Xf + ((size_t)b4 * N_ + n) * DI;
        float4 xa = *(const float4*)xp0;
        float4 xb = *(const float4*)(xp0 + 4);

        #pragma unroll 1
        for (int t = 0; t < 16; ++t) {
            const int b = b4 + 4 * t;
            const float4 cx0 = xa, cx1 = xb;
            if (t < 15) {   // prefetch next b's x while computing this one
                const float* xp = Xf + ((size_t)(b + 4) * N_ + n) * DI;
                xa = *(const float4*)xp;
                xb = *(const float4*)(xp + 4);
            }

            float u[O_];                       // u_hat[b, o=oo, d=c]
            #pragma unroll
            for (int oo = 0; oo < O_; ++oo) u[oo] = dot8(wA[oo], wB[oo], cx0, cx1);

            if (PHASE == 0) {
                #pragma unroll
                for (int oo = 0; oo < O_; ++oo)
                    atomicAdd(&s_lds[b * SROW + oo * DO_ + c], 0.1f * u[oo]);
            } else {
                // logits: t[o] = sum_d u_hat * v  (DPP reduce over 16 d-lanes)
                float tl[O_];
                #pragma unroll
                for (int oo = 0; oo < O_; ++oo) {
                    const float vv = blo((u32)v_lds[b * VROW + oo * DO_ + c]);
                    tl[oo] = row16_sum(u[oo] * vv);
                }
                // softmax over the 10 out-capsules (|t| small, no max-sub)
                float den = 0.0f;
                #pragma unroll
                for (int oo = 0; oo < O_; ++oo) { tl[oo] = __expf(tl[oo]); den += tl[oo]; }
                const float rinv = 1.0f / den;
                // weighting: reuse live u[] regs (no recompute)
                #pragma unroll
                for (int oo = 0; oo < O_; ++oo)
                    atomicAdd(&s_lds[b * SROW + oo * DO_ + c], (tl[oo] * rinv) * u[oo]);
            }
        }
    }
    __syncthreads();
    if (TAIL == 2) {
        for (int i = tid; i < B_ * OD; i += 512) {
            int bb = i / OD, od = i - bb * OD;
            atomicAdd(&Sout[i], s_lds[bb * SROW + od]);
        }
    } else {
        _Float16* my = Sh + (size_t)blockIdx.x * (B_ * OD);
        for (int i = tid; i < B_ * OD; i += 512) {
            int bb = i / OD, od = i - bb * OD;
            my[i] = (_Float16)s_lds[bb * SROW + od];
        }
    }
}

// Fused cross-block reduce + squash (norm over OUT-CAPSULE axis, per (b,d)).
// PHASE 0: V0f=v0 fp32, Vb=bf16(v0). PHASE 1: Vb=bf16(v0+v1). PHASE 2: out fp32.
// (Proven correct R5-R7.)
template <int PHASE>
__global__ __launch_bounds__(192)
void caps_reduce_fin(const _Float16* __restrict__ Sp, int nparts,
                     float* __restrict__ V0f, u16* __restrict__ Vb,
                     float* __restrict__ out) {
    __shared__ float s_s[OD];
    __shared__ float s_scale[DO_];
    const int b = blockIdx.x;
    const int t = threadIdx.x;
    if (t < OD) {
        float acc = 0.0f;
        const _Float16* p0 = Sp + b * OD + t;
        #pragma unroll 8
        for (int p = 0; p < nparts; ++p) acc += (float)p0[(size_t)p * (B_ * OD)];
        s_s[t] = acc;
    }
    __syncthreads();
    if (t < DO_) {
        float norm = 0.0f;
        #pragma unroll
        for (int o = 0; o < O_; ++o) { float x = s_s[o * DO_ + t]; norm = fmaf(x, x, norm); }
        s_scale[t] = norm / (1.0f + norm) * rsqrtf(norm + 1e-9f);
    }
    __syncthreads();
    if (t < OD) {
        const float v = s_s[t] * s_scale[t & 15];
        const int idx = b * OD + t;
        if (PHASE == 0) {
            V0f[idx] = v;
            __hip_bfloat16 h = __float2bfloat16(v);
            Vb[idx] = *(const u16*)&h;
        } else if (PHASE == 1) {
            const float vs = V0f[idx] + v;
            __hip_bfloat16 h = __float2bfloat16(vs);
            Vb[idx] = *(const u16*)&h;
        } else {
            out[idx] = v;
        }
    }
}

// Finalize for the atomic fallback (also zeroes S for the next pass).
template <int PHASE>
__global__ __launch_bounds__(1024)
void caps_finalize(float* __restrict__ S, float* __restrict__ V0f,
                   u16* __restrict__ Vb, float* __restrict__ out) {
    const int tid = threadIdx.x;      // 1024 = 64 b * 16 d
    const int b = tid >> 4, d = tid & 15;
    float sv[O_];
    float norm = 0.0f;
    #pragma unroll
    for (int o = 0; o < O_; ++o) {
        sv[o] = S[b * OD + o * DO_ + d];
        norm = fmaf(sv[o], sv[o], norm);
    }
    const float scale = norm / (1.0f + norm) * rsqrtf(norm + 1e-9f);
    #pragma unroll
    for (int o = 0; o < O_; ++o) {
        const int idx = b * OD + o * DO_ + d;
        const float v = scale * sv[o];
        if (PHASE == 0) {
            V0f[idx] = v;
            __hip_bfloat16 h = __float2bfloat16(v);
            Vb[idx] = *(const u16*)&h;
            S[idx] = 0.0f;
        } else if (PHASE == 1) {
            const float vs = V0f[idx] + v;
            __hip_bfloat16 h = __float2bfloat16(vs);
            Vb[idx] = *(const u16*)&h;
            S[idx] = 0.0f;
        } else {
            out[idx] = v;
        }
    }
}

extern "C" void kernel_launch(void* const* d_in, const int* in_sizes, int n_in,
                              void* d_out, int out_size, void* d_ws, size_t ws_size,
                              hipStream_t stream) {
    const float* Xf = (const float*)d_in[0];   // x: [64, 8192, 8] fp32
    const float* Wf = (const float*)d_in[1];   // W: [1, 8192, 10, 16, 8] fp32
    float* out = (float*)d_out;

    const size_t velems = (size_t)B_ * OD;                   // 10240
    const size_t base = velems * 4 + velems * 2;             // V0f fp32 + Vb bf16
    const size_t need = base + (size_t)NPART * velems * 2;   // 5,304,320 B (proven fits)

    float* V0f = (float*)d_ws;
    u16* Vb = (u16*)(V0f + velems);
    const dim3 grid(N_ / NCHUNK), blk(512), rgrid(B_), rblk(192);

    if (ws_size >= need) {
        // fast path: fp16 per-block partials (proven)
        _Float16* P = (_Float16*)((char*)d_ws + base);
        caps_pass<0, 1><<<grid, blk, 0, stream>>>(Xf, Wf, nullptr, nullptr, P);
        caps_reduce_fin<0><<<rgrid, rblk, 0, stream>>>(P, NPART, V0f, Vb, nullptr);
        caps_pass<1, 1><<<grid, blk, 0, stream>>>(Xf, Wf, Vb, nullptr, P);
        caps_reduce_fin<1><<<rgrid, rblk, 0, stream>>>(P, NPART, V0f, Vb, nullptr);
        caps_pass<1, 1><<<grid, blk, 0, stream>>>(Xf, Wf, Vb, nullptr, P);
        caps_reduce_fin<2><<<rgrid, rblk, 0, stream>>>(P, NPART, nullptr, nullptr, out);
    } else {
        // fallback: global atomic accumulator (proven R3 structure)
        float* S = (float*)((char*)d_ws + base);
        const dim3 one(1), fblk(1024);
        hipMemsetAsync(S, 0, velems * sizeof(float), stream);
        caps_pass<0, 2><<<grid, blk, 0, stream>>>(Xf, Wf, nullptr, S, nullptr);
        caps_finalize<0><<<one, fblk, 0, stream>>>(S, V0f, Vb, nullptr);
        caps_pass<1, 2><<<grid, blk, 0, stream>>>(Xf, Wf, Vb, S, nullptr);
        caps_finalize<1><<<one, fblk, 0, stream>>>(S, V0f, Vb, nullptr);
        caps_pass<1, 2><<<grid, blk, 0, stream>>>(Xf, Wf, Vb, S, nullptr);
        caps_finalize<2><<<one, fblk, 0, stream>>>(S, nullptr, nullptr, out);
    }
}